// Round 3
// baseline (124.964 us; speedup 1.0000x reference)
//
#include <hip/hip_runtime.h>
#include <hip/hip_bf16.h>
#include <math.h>

// Sizes fixed by the reference
#define NN 512
#define NQ 448
#define ND 64          // num_denoising
#define NC 91
#define ED 256
#define NH 8

struct FreqArg { float fr[32]; };

// All scratch in device globals — no dependence on ws_size.
__device__ int   g_perm[NN];
__device__ float g_WK[2048];      // 32 k * 4 f * 8 h * {sin,cos}
__device__ float g_w2a[NH * ED];
__device__ float g_c0[NH];
__device__ float g_afull[NN * NH];

// ---------------- Kernel A: scores -> stable descending argsort -> perm + rank_indices (f32) + zero afull[0:64]
__global__ __launch_bounds__(512) void precomp_rank(const float* __restrict__ logits,
                                                    float* __restrict__ out2) {
    __shared__ float sc[NQ];
    int t = threadIdx.x;
    if (t < NQ) {
        const float* row = logits + (size_t)(ND + t) * NC;
        float m = row[0];
        for (int c = 1; c < NC; ++c) m = fmaxf(m, row[c]);
        sc[t] = 1.0f / (1.0f + expf(-m));   // sigmoid(max) == max(sigmoid), monotone
    }
    __syncthreads();
    if (t < NQ) {
        float s = sc[t];
        int rank = 0;
        for (int j = 0; j < NQ; ++j) {
            float sj = sc[j];
            rank += ((sj > s) || (sj == s && j < t)) ? 1 : 0;   // stable descending
        }
        g_perm[ND + rank] = ND + t;
        out2[ND + rank] = (float)(ND + t);
    }
    if (t < ND) {
        g_perm[t] = t;
        out2[t] = (float)t;
        for (int h = 0; h < NH; ++h) g_afull[t * NH + h] = 0.f;
    }
}

// ---------------- Kernel B: fold attn_W through post_W -> WK (sin/cos weights), w2a, c0
__global__ __launch_bounds__(256) void precomp_w(const float* __restrict__ attn_W,
                                                 const float* __restrict__ attn_b,
                                                 const float* __restrict__ post_W,
                                                 const float* __restrict__ post_b) {
    int d = threadIdx.x;  // 0..255
    for (int h = 0; h < NH; ++h) {
        float m1 = 0.f, m2 = 0.f;
        for (int c = 0; c < ED; ++c) {
            float aw = attn_W[h * ED + c];
            m1 = fmaf(aw, post_W[(size_t)c * 512 + d], m1);        // W1 part (pos)
            m2 = fmaf(aw, post_W[(size_t)c * 512 + 256 + d], m2);  // W2 part (rank_rel)
        }
        // d = f*64 + 2k + r  ->  WK[(k*4+f)*16 + h*2 + r]
        int f = d >> 6, rem = d & 63, k = rem >> 1, r = rem & 1;
        g_WK[(k * 4 + f) * 16 + h * 2 + r] = m1;
        g_w2a[h * ED + d] = m2;
    }
    if (d < NH) {
        float cc = attn_b[d];
        for (int c = 0; c < ED; ++c) cc = fmaf(attn_W[d * ED + c], post_b[c], cc);
        g_c0[d] = cc;
    }
}

// ---------------- Kernel C: normal_rank row (in LDS) -> a[q,h] into afull[64+q]
__global__ __launch_bounds__(256) void precomp_a(const float* __restrict__ rank_emb,
                                                 const float* __restrict__ pre_W,
                                                 const float* __restrict__ pre_b) {
    __shared__ float remb[ED];
    __shared__ float nr[ED];
    int q = blockIdx.x, d = threadIdx.x;
    remb[d] = rank_emb[(size_t)q * ED + d];
    __syncthreads();
    float s = pre_b[d];
    const float* wrow = pre_W + (size_t)d * ED;
    for (int e = 0; e < ED; ++e) s = fmaf(remb[e], wrow[e], s);
    nr[d] = s;
    __syncthreads();
    if (d < NH) {
        float a = 0.f;
        const float* w = g_w2a + d * ED;
        for (int e = 0; e < ED; ++e) a = fmaf(w[e], nr[e], a);
        g_afull[(size_t)(ND + q) * NH + d] = a;
    }
}

// ---------------- Kernel D: main per-pair kernel (f32 output)
__global__ __launch_bounds__(256) void relation_main(const float* __restrict__ boxes,
                                                     FreqArg fa,
                                                     float* __restrict__ out) {
    int idx = blockIdx.x * 256 + threadIdx.x;
    int i = idx >> 9, j = idx & (NN - 1);
    int pi = i, pj = j;
    if (i >= ND && j >= ND) { pi = g_perm[i]; pj = g_perm[j]; }
    float4 b1 = ((const float4*)boxes)[pi];
    float4 b2 = ((const float4*)boxes)[pj];
    const float eps = 1e-5f;
    float feat[4];
    feat[0] = logf(fabsf(b1.x - b2.x) / (b1.z + eps) + 1.0f);
    feat[1] = logf(fabsf(b1.y - b2.y) / (b1.w + eps) + 1.0f);
    feat[2] = logf((b1.z + eps) / (b2.z + eps));
    feat[3] = logf((b1.w + eps) / (b2.w + eps));

    float acc[NH];
#pragma unroll
    for (int h = 0; h < NH; ++h) acc[h] = g_c0[h] + g_afull[i * NH + h] + g_afull[j * NH + h];

#pragma unroll
    for (int k = 0; k < 32; ++k) {
        float fr = fa.fr[k];
#pragma unroll
        for (int f = 0; f < 4; ++f) {
            float rev = feat[f] * fr;           // angle in revolutions
            rev = rev - floorf(rev);            // v_fract: safe domain for v_sin/v_cos
            float s = __builtin_amdgcn_sinf(rev);   // sin(2*pi*rev)
            float c = __builtin_amdgcn_cosf(rev);
            const float* w = g_WK + (k * 4 + f) * 16;
#pragma unroll
            for (int h = 0; h < NH; ++h) {
                acc[h] = fmaf(s, w[h * 2 + 0], acc[h]);
                acc[h] = fmaf(c, w[h * 2 + 1], acc[h]);
            }
        }
    }
#pragma unroll
    for (int h = 0; h < NH; ++h) {
        float v = acc[h] > 0.f ? acc[h] : 0.f;  // relu
        out[(size_t)h * (NN * NN) + idx] = v;
    }
}

extern "C" void kernel_launch(void* const* d_in, const int* in_sizes, int n_in,
                              void* d_out, int out_size, void* d_ws, size_t ws_size,
                              hipStream_t stream) {
    const float* boxes    = (const float*)d_in[0];
    const float* logits   = (const float*)d_in[1];
    const float* rank_emb = (const float*)d_in[2];
    const float* pre_W    = (const float*)d_in[3];
    const float* pre_b    = (const float*)d_in[4];
    const float* post_W   = (const float*)d_in[5];
    const float* post_b   = (const float*)d_in[6];
    const float* attn_W   = (const float*)d_in[7];
    const float* attn_b   = (const float*)d_in[8];
    float* out = (float*)d_out;

    precomp_rank<<<1, 512, 0, stream>>>(logits, out + (size_t)NH * NN * NN);
    precomp_w<<<1, 256, 0, stream>>>(attn_W, attn_b, post_W, post_b);
    precomp_a<<<NQ, 256, 0, stream>>>(rank_emb, pre_W, pre_b);

    FreqArg fa;
    for (int k = 0; k < 32; ++k)
        fa.fr[k] = (float)(100.0 / (2.0 * M_PI) / pow(10000.0, (double)k / 32.0));

    relation_main<<<(NN * NN) / 256, 256, 0, stream>>>(boxes, fa, out);
}

// Round 4
// 70.009 us; speedup vs baseline: 1.7850x; 1.7850x over previous
//
#include <hip/hip_runtime.h>
#include <hip/hip_bf16.h>
#include <math.h>

// Sizes fixed by the reference
#define NN 512
#define NQ 448
#define ND 64          // num_denoising
#define NC 91
#define ED 256
#define NH 8

struct FreqArg { float fr[32]; };

// All scratch in device globals — no dependence on ws_size.
__device__ int   g_perm[NN];
__device__ float g_WK[2048];      // 32 k * 4 f * 8 h * {sin,cos}
__device__ float g_w2a[NH * ED];
__device__ float g_c0[NH];
__device__ float g_afull[NN * NH];

// ---------------- Kernel 1: block 0 = rank/argsort; blocks 1..8 = fold attn_W@post_W (h=bid-1); block 9 = c0
__global__ __launch_bounds__(512) void precomp_all(const float* __restrict__ logits,
                                                   const float* __restrict__ attn_W,
                                                   const float* __restrict__ attn_b,
                                                   const float* __restrict__ post_W,
                                                   const float* __restrict__ post_b,
                                                   float* __restrict__ out2) {
    int bid = blockIdx.x;
    int t = threadIdx.x;
    if (bid == 0) {
        // scores -> stable descending argsort -> perm + rank_indices (f32) + zero afull[0:64]
        __shared__ float sc[NQ];
        if (t < NQ) {
            const float* row = logits + (size_t)(ND + t) * NC;
            float m = row[0];
            for (int c = 1; c < NC; ++c) m = fmaxf(m, row[c]);
            sc[t] = 1.0f / (1.0f + expf(-m));   // sigmoid(max) == max(sigmoid), monotone
        }
        __syncthreads();
        if (t < NQ) {
            float s = sc[t];
            int rank = 0;
            for (int j = 0; j < NQ; ++j) {
                float sj = sc[j];
                rank += ((sj > s) || (sj == s && j < t)) ? 1 : 0;   // stable descending
            }
            g_perm[ND + rank] = ND + t;
            out2[ND + rank] = (float)(ND + t);
        }
        if (t < ND) {
            g_perm[t] = t;
            out2[t] = (float)t;
            for (int h = 0; h < NH; ++h) g_afull[t * NH + h] = 0.f;
        }
    } else if (bid <= NH) {
        // one head per block; threads 0-255: m1 (pos weights), 256-511: m2 (rank weights)
        int h = bid - 1;
        int d = t & 255;
        int part = t >> 8;                 // 0 -> m1, 1 -> m2
        const float* aw = attn_W + h * ED; // uniform per block -> scalarized loads
        const float* pw = post_W + part * 256 + d;
        float m = 0.f;
        for (int c = 0; c < ED; ++c) m = fmaf(aw[c], pw[(size_t)c * 512], m);
        if (part == 0) {
            // d = f*64 + 2k + r  ->  WK[(k*4+f)*16 + h*2 + r]
            int f = d >> 6, rem = d & 63, k = rem >> 1, r = rem & 1;
            g_WK[(k * 4 + f) * 16 + h * 2 + r] = m;
        } else {
            g_w2a[h * ED + d] = m;
        }
    } else {
        // c0[h] = attn_b[h] + attn_W[h,:] @ post_b
        if (t < NH) {
            float cc = attn_b[t];
            for (int c = 0; c < ED; ++c) cc = fmaf(attn_W[t * ED + c], post_b[c], cc);
            g_c0[t] = cc;
        }
    }
}

// ---------------- Kernel 2: normal_rank row (in LDS) -> a[q,h] into afull[64+q]
__global__ __launch_bounds__(256) void precomp_a(const float* __restrict__ rank_emb,
                                                 const float* __restrict__ pre_W,
                                                 const float* __restrict__ pre_b) {
    __shared__ float remb[ED];
    __shared__ float nr[ED];
    int q = blockIdx.x, d = threadIdx.x;
    remb[d] = rank_emb[(size_t)q * ED + d];
    __syncthreads();
    float s = pre_b[d];
    const float* wrow = pre_W + (size_t)d * ED;
    for (int e = 0; e < ED; ++e) s = fmaf(remb[e], wrow[e], s);
    nr[d] = s;
    __syncthreads();
    if (d < NH) {
        float a = 0.f;
        const float* w = g_w2a + d * ED;
        for (int e = 0; e < ED; ++e) a = fmaf(w[e], nr[e], a);
        g_afull[(size_t)(ND + q) * NH + d] = a;
    }
}

// ---------------- Kernel 3: main per-pair kernel (f32 output)
__global__ __launch_bounds__(256) void relation_main(const float* __restrict__ boxes,
                                                     FreqArg fa,
                                                     float* __restrict__ out) {
    int idx = blockIdx.x * 256 + threadIdx.x;
    int i = idx >> 9, j = idx & (NN - 1);
    int pi = i, pj = j;
    if (i >= ND && j >= ND) { pi = g_perm[i]; pj = g_perm[j]; }
    float4 b1 = ((const float4*)boxes)[pi];
    float4 b2 = ((const float4*)boxes)[pj];
    const float eps = 1e-5f;
    float feat[4];
    feat[0] = logf(fabsf(b1.x - b2.x) / (b1.z + eps) + 1.0f);
    feat[1] = logf(fabsf(b1.y - b2.y) / (b1.w + eps) + 1.0f);
    feat[2] = logf((b1.z + eps) / (b2.z + eps));
    feat[3] = logf((b1.w + eps) / (b2.w + eps));

    float acc[NH];
#pragma unroll
    for (int h = 0; h < NH; ++h) acc[h] = g_c0[h] + g_afull[i * NH + h] + g_afull[j * NH + h];

#pragma unroll
    for (int k = 0; k < 32; ++k) {
        float fr = fa.fr[k];
#pragma unroll
        for (int f = 0; f < 4; ++f) {
            float rev = feat[f] * fr;           // angle in revolutions
            rev = rev - floorf(rev);            // v_fract: safe domain for v_sin/v_cos
            float s = __builtin_amdgcn_sinf(rev);   // sin(2*pi*rev)
            float c = __builtin_amdgcn_cosf(rev);
            const float* w = g_WK + (k * 4 + f) * 16;
#pragma unroll
            for (int h = 0; h < NH; ++h) {
                acc[h] = fmaf(s, w[h * 2 + 0], acc[h]);
                acc[h] = fmaf(c, w[h * 2 + 1], acc[h]);
            }
        }
    }
#pragma unroll
    for (int h = 0; h < NH; ++h) {
        float v = acc[h] > 0.f ? acc[h] : 0.f;  // relu
        out[(size_t)h * (NN * NN) + idx] = v;
    }
}

extern "C" void kernel_launch(void* const* d_in, const int* in_sizes, int n_in,
                              void* d_out, int out_size, void* d_ws, size_t ws_size,
                              hipStream_t stream) {
    const float* boxes    = (const float*)d_in[0];
    const float* logits   = (const float*)d_in[1];
    const float* rank_emb = (const float*)d_in[2];
    const float* pre_W    = (const float*)d_in[3];
    const float* pre_b    = (const float*)d_in[4];
    const float* post_W   = (const float*)d_in[5];
    const float* post_b   = (const float*)d_in[6];
    const float* attn_W   = (const float*)d_in[7];
    const float* attn_b   = (const float*)d_in[8];
    float* out = (float*)d_out;

    precomp_all<<<10, 512, 0, stream>>>(logits, attn_W, attn_b, post_W, post_b,
                                        out + (size_t)NH * NN * NN);
    precomp_a<<<NQ, 256, 0, stream>>>(rank_emb, pre_W, pre_b);

    FreqArg fa;
    for (int k = 0; k < 32; ++k)
        fa.fr[k] = (float)(100.0 / (2.0 * M_PI) / pow(10000.0, (double)k / 32.0));

    relation_main<<<(NN * NN) / 256, 256, 0, stream>>>(boxes, fa, out);
}

// Round 5
// 67.030 us; speedup vs baseline: 1.8643x; 1.0445x over previous
//
#include <hip/hip_runtime.h>
#include <hip/hip_bf16.h>
#include <math.h>

// Sizes fixed by the reference
#define NN 512
#define NQ 448
#define ND 64          // num_denoising
#define NC 91
#define ED 256
#define NH 8

struct FreqArg { float fr[32]; };

// All scratch in device globals — no dependence on ws_size.
__device__ int   g_perm[NN];
__device__ float g_WK[2048];      // 32 k * 4 f * 8 h * {sin,cos}
__device__ float g_w2a[NH * ED];
__device__ float g_c0[NH];
__device__ float g_u[NH * ED];    // u[h,c] = sum_d w2a[h,d] * pre_W[d,c]
__device__ float g_b2a[NH];       // sum_d w2a[h,d] * pre_b[d]
__device__ float g_afull[NN * NH];

// ---------------- K1: block 0 = rank/argsort; blocks 1..8 = fold attn_W@post_W (h=bid-1); block 9 = c0
__global__ __launch_bounds__(512) void precomp_all(const float* __restrict__ logits,
                                                   const float* __restrict__ attn_W,
                                                   const float* __restrict__ attn_b,
                                                   const float* __restrict__ post_W,
                                                   const float* __restrict__ post_b,
                                                   float* __restrict__ out2) {
    int bid = blockIdx.x;
    int t = threadIdx.x;
    if (bid == 0) {
        // scores -> stable descending argsort -> perm + rank_indices (f32) + zero afull[0:64]
        __shared__ float sc[NQ];
        if (t < NQ) {
            const float* row = logits + (size_t)(ND + t) * NC;
            float m = row[0];
            for (int c = 1; c < NC; ++c) m = fmaxf(m, row[c]);
            sc[t] = 1.0f / (1.0f + expf(-m));   // sigmoid(max) == max(sigmoid), monotone
        }
        __syncthreads();
        if (t < NQ) {
            float s = sc[t];
            int rank = 0;
            for (int j = 0; j < NQ; ++j) {
                float sj = sc[j];
                rank += ((sj > s) || (sj == s && j < t)) ? 1 : 0;   // stable descending
            }
            g_perm[ND + rank] = ND + t;
            out2[ND + rank] = (float)(ND + t);
        }
        if (t < ND) {
            g_perm[t] = t;
            out2[t] = (float)t;
            for (int h = 0; h < NH; ++h) g_afull[t * NH + h] = 0.f;
        }
    } else if (bid <= NH) {
        // one head per block; threads 0-255: m1 (pos weights), 256-511: m2 (rank weights)
        __shared__ float sAW[ED];           // LDS-stage attn_W row: in-order ds_read, no SMEM drain
        int h = bid - 1;
        if (t < ED) sAW[t] = attn_W[h * ED + t];
        __syncthreads();
        int d = t & 255;
        int part = t >> 8;                  // 0 -> m1, 1 -> m2
        const float* pw = post_W + part * 256 + d;
        float m = 0.f;
        for (int c = 0; c < ED; ++c) m = fmaf(sAW[c], pw[(size_t)c * 512], m);
        if (part == 0) {
            // d = f*64 + 2k + r  ->  WK[(k*4+f)*16 + h*2 + r]
            int f = d >> 6, rem = d & 63, k = rem >> 1, r = rem & 1;
            g_WK[(k * 4 + f) * 16 + h * 2 + r] = m;
        } else {
            g_w2a[h * ED + d] = m;
        }
    } else {
        // c0[h] = attn_b[h] + attn_W[h,:] @ post_b
        if (t < NH) {
            float cc = attn_b[t];
            for (int c = 0; c < ED; ++c) cc = fmaf(attn_W[t * ED + c], post_b[c], cc);
            g_c0[t] = cc;
        }
    }
}

// ---------------- K2: u[h,:] = w2a[h,:] @ pre_W  (coalesced over c), b2a[h] via block reduce
__global__ __launch_bounds__(256) void precomp_u(const float* __restrict__ pre_W,
                                                 const float* __restrict__ pre_b) {
    int h = blockIdx.x, c = threadIdx.x;
    __shared__ float sW[ED];
    __shared__ float red[ED];
    sW[c] = g_w2a[h * ED + c];
    __syncthreads();
    float acc = 0.f;
    for (int d = 0; d < ED; ++d) acc = fmaf(sW[d], pre_W[(size_t)d * ED + c], acc);
    g_u[h * ED + c] = acc;
    red[c] = sW[c] * pre_b[c];
    __syncthreads();
    for (int s2 = 128; s2 > 0; s2 >>= 1) {
        if (c < s2) red[c] += red[c + s2];
        __syncthreads();
    }
    if (c == 0) g_b2a[h] = red[0];
}

// ---------------- K3: afull[64+q,h] = b2a[h] + remb[q,:] @ u[h,:]   (32 q x 8 h per block)
__global__ __launch_bounds__(256) void precomp_afull(const float* __restrict__ rank_emb) {
    __shared__ float sU[NH][ED + 1];    // +1 pad: lanes differ in h -> distinct banks
    __shared__ float sR[32][ED + 1];    // +1 pad: lanes differ in qloc -> distinct banks
    int t = threadIdx.x;
    int q0 = blockIdx.x * 32;
    for (int v = t; v < NH * ED; v += 256) sU[v >> 8][v & 255] = g_u[v];
    for (int v = t; v < 32 * ED; v += 256)
        sR[v >> 8][v & 255] = rank_emb[(size_t)(q0 + (v >> 8)) * ED + (v & 255)];
    __syncthreads();
    int qloc = t >> 3, h = t & 7;
    float acc = g_b2a[h];
    for (int c = 0; c < ED; ++c) acc = fmaf(sR[qloc][c], sU[h][c], acc);
    g_afull[(size_t)(ND + q0 + qloc) * NH + h] = acc;
}

// ---------------- K4: main per-pair kernel (f32 output), WK staged in LDS
__global__ __launch_bounds__(256) void relation_main(const float* __restrict__ boxes,
                                                     FreqArg fa,
                                                     float* __restrict__ out) {
    __shared__ float sWK[2048];
    int t = threadIdx.x;
    for (int v = t; v < 2048; v += 256) sWK[v] = g_WK[v];
    __syncthreads();

    int idx = blockIdx.x * 256 + t;
    int i = idx >> 9, j = idx & (NN - 1);
    int pi = i, pj = j;
    if (i >= ND && j >= ND) { pi = g_perm[i]; pj = g_perm[j]; }
    float4 b1 = ((const float4*)boxes)[pi];
    float4 b2 = ((const float4*)boxes)[pj];
    const float eps = 1e-5f;
    float feat[4];
    feat[0] = logf(fabsf(b1.x - b2.x) / (b1.z + eps) + 1.0f);
    feat[1] = logf(fabsf(b1.y - b2.y) / (b1.w + eps) + 1.0f);
    feat[2] = logf((b1.z + eps) / (b2.z + eps));
    feat[3] = logf((b1.w + eps) / (b2.w + eps));

    float acc[NH];
#pragma unroll
    for (int h = 0; h < NH; ++h) acc[h] = g_c0[h] + g_afull[i * NH + h] + g_afull[j * NH + h];

#pragma unroll 8
    for (int k = 0; k < 32; ++k) {
        float fr = fa.fr[k];
#pragma unroll
        for (int f = 0; f < 4; ++f) {
            float rev = feat[f] * fr;           // angle in revolutions
            rev = rev - floorf(rev);            // v_fract: safe domain for v_sin/v_cos
            float s = __builtin_amdgcn_sinf(rev);   // sin(2*pi*rev)
            float c = __builtin_amdgcn_cosf(rev);
            const float* w = sWK + ((k * 4 + f) << 4);   // uniform ds_read_b128 x4, broadcast
#pragma unroll
            for (int h = 0; h < NH; ++h) {
                acc[h] = fmaf(s, w[h * 2 + 0], acc[h]);
                acc[h] = fmaf(c, w[h * 2 + 1], acc[h]);
            }
        }
    }
#pragma unroll
    for (int h = 0; h < NH; ++h) {
        float v = acc[h] > 0.f ? acc[h] : 0.f;  // relu
        out[(size_t)h * (NN * NN) + idx] = v;
    }
}

extern "C" void kernel_launch(void* const* d_in, const int* in_sizes, int n_in,
                              void* d_out, int out_size, void* d_ws, size_t ws_size,
                              hipStream_t stream) {
    const float* boxes    = (const float*)d_in[0];
    const float* logits   = (const float*)d_in[1];
    const float* rank_emb = (const float*)d_in[2];
    const float* pre_W    = (const float*)d_in[3];
    const float* pre_b    = (const float*)d_in[4];
    const float* post_W   = (const float*)d_in[5];
    const float* post_b   = (const float*)d_in[6];
    const float* attn_W   = (const float*)d_in[7];
    const float* attn_b   = (const float*)d_in[8];
    float* out = (float*)d_out;

    precomp_all<<<10, 512, 0, stream>>>(logits, attn_W, attn_b, post_W, post_b,
                                        out + (size_t)NH * NN * NN);
    precomp_u<<<NH, 256, 0, stream>>>(pre_W, pre_b);
    precomp_afull<<<NQ / 32, 256, 0, stream>>>(rank_emb);

    FreqArg fa;
    for (int k = 0; k < 32; ++k)
        fa.fr[k] = (float)(100.0 / (2.0 * M_PI) / pow(10000.0, (double)k / 32.0));

    relation_main<<<(NN * NN) / 256, 256, 0, stream>>>(boxes, fa, out);
}